// Round 4
// baseline (169.527 us; speedup 1.0000x reference)
//
#include <hip/hip_runtime.h>

#define N_NODES 50000
#define NPB 128                               // nodes per bucket
#define NBUCKET ((N_NODES + NPB - 1) / NPB)   // 391
#define CAP 2816                              // edges per bucket region (mean 2046 + ~17 sigma)
#define CHUNK 2048                            // edges per partition block
#define EPT 4                                 // edges per thread in k_part (CHUNK/512)

// ---------------- partition: LDS counting-sort per chunk, coalesced run writes ----
// edge word: src(16b) | ldst(7b)<<16 | bucket(9b)<<23   (src < 50000 < 65536)
// gcursor pre-zeroed by memset; holds RELATIVE per-bucket fill counts.

__global__ __launch_bounds__(512) void k_part(const int* __restrict__ src,
                                              const int* __restrict__ dst,
                                              int* __restrict__ gcursor,
                                              int* __restrict__ ewords, int E) {
    __shared__ int words[CHUNK];   // 8 KB
    __shared__ int hist[512];      // hist -> cursor
    __shared__ int lstart[512];
    __shared__ int gbase[512];
    __shared__ int wsum[8];

    int tid = threadIdx.x;
    int cbase = blockIdx.x * CHUNK;
    int count = min(CHUNK, E - cbase);

    hist[tid] = 0;
    __syncthreads();

    // phase 1: load edges (vectorized except tail block), histogram buckets
    int w[EPT];
    if (cbase + CHUNK <= E) {
        int4 s4 = ((const int4*)(src + cbase))[tid];
        int4 d4 = ((const int4*)(dst + cbase))[tid];
        int ss[EPT] = {s4.x, s4.y, s4.z, s4.w};
        int dd[EPT] = {d4.x, d4.y, d4.z, d4.w};
#pragma unroll
        for (int r = 0; r < EPT; r++) {
            int b = dd[r] >> 7;
            w[r] = ss[r] | ((dd[r] & 127) << 16) | (b << 23);
            atomicAdd(&hist[b], 1);
        }
    } else {
#pragma unroll
        for (int r = 0; r < EPT; r++) {
            int i = tid * EPT + r;     // local index
            if (i < count) {
                int s = src[cbase + i];
                int d = dst[cbase + i];
                int b = d >> 7;
                w[r] = s | ((d & 127) << 16) | (b << 23);
                atomicAdd(&hist[b], 1);
            } else {
                w[r] = -1;
            }
        }
    }
    __syncthreads();

    // phase 2: exclusive scan of hist[512] -- wave shfl scan + cross-wave fixup
    int h = hist[tid];
    int lane = tid & 63;
    int v = h;
#pragma unroll
    for (int off = 1; off < 64; off <<= 1) {
        int t = __shfl_up(v, off, 64);
        if (lane >= off) v += t;
    }
    if (lane == 63) wsum[tid >> 6] = v;
    __syncthreads();
    int woff = 0;
    int wv = tid >> 6;
    for (int i = 0; i < wv; i++) woff += wsum[i];
    int excl = v + woff - h;
    hist[tid] = excl;       // becomes local cursor
    lstart[tid] = excl;
    __syncthreads();

    // phase 3: scatter words into LDS grouped by bucket
#pragma unroll
    for (int r = 0; r < EPT; r++) {
        if (w[r] != -1) {
            int b = ((unsigned)w[r]) >> 23;
            int pos = atomicAdd(&hist[b], 1);
            words[pos] = w[r];
        }
    }
    __syncthreads();

    // phase 4: one global cursor bump per bucket per chunk (relative offsets)
    if (tid < NBUCKET) {
        int nb = hist[tid] - lstart[tid];
        gbase[tid] = (nb > 0) ? atomicAdd(&gcursor[tid], nb) : 0;
    }
    __syncthreads();

    // phase 5: coalesced run write-out
    for (int i = tid; i < count; i += 512) {
        int ww = words[i];
        int b = ((unsigned)ww) >> 23;
        ewords[b * CAP + gbase[b] + (i - lstart[b])] = ww;
    }
}

// ---------------- fused: per-bucket counting sort (blocks < NBUCKET)  |
//                         gemm1 h1 = x @ W1, unscaled (blocks >= NBUCKET) ----------

__global__ __launch_bounds__(256) void k_sortgemm1(const int* __restrict__ ewords,
                                                   const int* __restrict__ gcursor,
                                                   unsigned short* __restrict__ eidx,
                                                   int* __restrict__ row_start,
                                                   int* __restrict__ deg,
                                                   float* __restrict__ dinv,
                                                   const float* __restrict__ x,
                                                   const float* __restrict__ W1,
                                                   float* __restrict__ h1) {
    __shared__ __align__(16) char smem[16 * 132 * 4 * 2];   // 16,896 B union
    int tid = threadIdx.x;

    if (blockIdx.x < NBUCKET) {
        // ---- sort role ----
        unsigned short* sorted = (unsigned short*)smem;        // CAP*2 = 5632 B
        int* hist = (int*)(smem + 5632);                       // 128*4
        int* sc   = (int*)(smem + 5632 + 512);                 // 128*4

        int b = blockIdx.x;
        int base = b * CAP;
        int count = gcursor[b];                                // relative count

        if (tid < NPB) hist[tid] = 0;
        __syncthreads();

        int w[(CAP + 255) / 256];   // 11
#pragma unroll
        for (int r = 0; r < (CAP + 255) / 256; r++) {
            int i = tid + 256 * r;
            if (i < count) {
                int ww = ewords[base + i];
                w[r] = ww;
                atomicAdd(&hist[(ww >> 16) & 127], 1);
            } else {
                w[r] = -1;
            }
        }
        __syncthreads();

        // exclusive scan of hist[128]
        int v = 0;
        if (tid < NPB) { v = hist[tid]; sc[tid] = v; }
        __syncthreads();
        for (int off = 1; off < NPB; off <<= 1) {
            int t = 0;
            if (tid < NPB && tid >= off) t = sc[tid - off];
            __syncthreads();
            if (tid < NPB) sc[tid] += t;
            __syncthreads();
        }
        if (tid < NPB) {
            int excl = sc[tid] - v;
            int node = b * NPB + tid;
            if (node < N_NODES) {
                row_start[node] = base + excl;
                deg[node] = v;
                dinv[node] = rsqrtf((float)(v + 1));
            }
            hist[tid] = excl;   // cursor
        }
        __syncthreads();

#pragma unroll
        for (int r = 0; r < (CAP + 255) / 256; r++) {
            if (w[r] != -1) {
                int ldst = (w[r] >> 16) & 127;
                int pos = atomicAdd(&hist[ldst], 1);
                sorted[pos] = (unsigned short)(w[r] & 0xFFFF);
            }
        }
        __syncthreads();

        for (int i = tid; i < count; i += 256) eidx[base + i] = sorted[i];
    } else {
        // ---- gemm1 role: 16 nodes per block ----
        float* sx  = (float*)smem;              // 16*132
        float* swT = sx + 16 * 132;             // 16*132
        int n0 = (blockIdx.x - NBUCKET) * 16;

#pragma unroll
        for (int r = 0; r < 2; r++) {
            int q = tid + 256 * r;
            float4 v = ((const float4*)W1)[q];
            int k = q >> 2;
            int j4 = (q & 3) << 2;
            swT[(j4 + 0) * 132 + k] = v.x;
            swT[(j4 + 1) * 132 + k] = v.y;
            swT[(j4 + 2) * 132 + k] = v.z;
            swT[(j4 + 3) * 132 + k] = v.w;
        }
        const float4* x4 = (const float4*)(x + (size_t)n0 * 128);
#pragma unroll
        for (int r = 0; r < 2; r++) {
            int q = tid + 256 * r;
            float4 v = x4[q];
            int node = q >> 5;
            int k = (q & 31) << 2;
            *(float4*)&sx[node * 132 + k] = v;
        }
        __syncthreads();

        int node = tid >> 4;
        int j = tid & 15;
        float acc = 0.f;
#pragma unroll
        for (int k = 0; k < 128; k += 4) {
            float4 a = *(const float4*)&sx[node * 132 + k];
            float4 bb = *(const float4*)&swT[j * 132 + k];
            acc = fmaf(a.x, bb.x, acc);
            acc = fmaf(a.y, bb.y, acc);
            acc = fmaf(a.z, bb.z, acc);
            acc = fmaf(a.w, bb.w, acc);
        }
        h1[(size_t)(n0 + node) * 16 + j] = acc;
    }
}

// ---------------- agg1: one wave per node; per-edge dinv[src]; relu epilogue ------
// z1s[n] = dinv[n] * relu(dinv[n]*(sum_e dinv[s]*h1[s] + dinv[n]*h1[n]) + b1)

__global__ __launch_bounds__(256) void k_agg1(const float* __restrict__ h1,
                                              const int* __restrict__ row_start,
                                              const int* __restrict__ deg,
                                              const unsigned short* __restrict__ eidx,
                                              const float* __restrict__ dinv,
                                              const float* __restrict__ b1,
                                              float* __restrict__ z1s) {
    int lane = threadIdx.x & 63;
    int node = blockIdx.x * 4 + (threadIdx.x >> 6);   // grid = N/4 exactly
    int f = lane & 15;
    int sub = lane >> 4;

    int start = row_start[node];
    int d = deg[node];

    float a0 = 0.f, a1 = 0.f;
    int i = sub;
    for (; i + 4 < d; i += 8) {
        int s0 = eidx[start + i];
        int s1 = eidx[start + i + 4];
        float d0 = dinv[s0];
        float d1 = dinv[s1];
        a0 = fmaf(d0, h1[s0 * 16 + f], a0);
        a1 = fmaf(d1, h1[s1 * 16 + f], a1);
    }
    if (i < d) {
        int s = eidx[start + i];
        a0 = fmaf(dinv[s], h1[s * 16 + f], a0);
    }
    float acc = a0 + a1;

    acc += __shfl_xor(acc, 16, 64);
    acc += __shfl_xor(acc, 32, 64);

    float dv = dinv[node];
    acc = fmaf(dv, h1[node * 16 + f], acc);            // self loop
    float z = fmaxf(fmaf(dv, acc, b1[f]), 0.f);
    if (sub == 0) z1s[node * 16 + f] = dv * z;         // pre-scaled for layer 2
}

// ---------------- fused agg2 + gemm2: one wave -> 16 nodes ------------------------
// s2 = dinv[n]*(sum_e z1s[s] + z1s[n]);  out[n][j] = b2[j] + sum_k s2[k]*W2[k][j]

__global__ __launch_bounds__(256) void k_aggmm(const float* __restrict__ z1s,
                                               const int* __restrict__ row_start,
                                               const int* __restrict__ deg,
                                               const unsigned short* __restrict__ eidx,
                                               const float* __restrict__ dinv,
                                               const float* __restrict__ W2,
                                               const float* __restrict__ b2,
                                               float* __restrict__ out) {
    __shared__ float sw2[16 * 128];   // [k][j], 8 KB
    __shared__ float sb2[128];
    int tid = threadIdx.x;

    ((float4*)sw2)[tid] = ((const float4*)W2)[tid];
    ((float4*)sw2)[tid + 256] = ((const float4*)W2)[tid + 256];
    if (tid < 32) ((float4*)sb2)[tid] = ((const float4*)b2)[tid];
    __syncthreads();

    int wave = tid >> 6;
    int lane = tid & 63;
    int f = lane & 15;
    int sub = lane >> 4;
    int nbase = (blockIdx.x * 4 + wave) * 16;

#pragma unroll 1
    for (int t = 0; t < 16; t++) {
        int node = nbase + t;
        if (node >= N_NODES) break;

        int start = row_start[node];
        int d = deg[node];

        float a0 = 0.f, a1 = 0.f;
        int i = sub;
        for (; i + 4 < d; i += 8) {
            int s0 = eidx[start + i];
            int s1 = eidx[start + i + 4];
            a0 += z1s[s0 * 16 + f];
            a1 += z1s[s1 * 16 + f];
        }
        if (i < d) a0 += z1s[(int)eidx[start + i] * 16 + f];
        float acc = a0 + a1;

        acc += __shfl_xor(acc, 16, 64);
        acc += __shfl_xor(acc, 32, 64);
        acc += z1s[node * 16 + f];                 // self loop (pre-scaled)
        float s2 = dinv[node] * acc;               // all 64 lanes hold s2 for f=lane&15

        float o0 = sb2[lane];
        float o1 = sb2[lane + 64];
#pragma unroll
        for (int k = 0; k < 16; k++) {
            float sk = __shfl(s2, k, 64);          // lane k has f==k
            o0 = fmaf(sk, sw2[k * 128 + lane], o0);
            o1 = fmaf(sk, sw2[k * 128 + 64 + lane], o1);
        }
        out[(size_t)node * 128 + lane] = o0;
        out[(size_t)node * 128 + 64 + lane] = o1;
    }
}

// ---------------- launch ----------------

extern "C" void kernel_launch(void* const* d_in, const int* in_sizes, int n_in,
                              void* d_out, int out_size, void* d_ws, size_t ws_size,
                              hipStream_t stream) {
    const float* x  = (const float*)d_in[0];
    const int*   ei = (const int*)d_in[1];
    const float* W1 = (const float*)d_in[2];
    const float* b1 = (const float*)d_in[3];
    const float* W2 = (const float*)d_in[4];
    const float* b2 = (const float*)d_in[5];
    float* out = (float*)d_out;

    const int E = in_sizes[1] / 2;            // 800000
    const int* src = ei;
    const int* dst = ei + E;

    // workspace layout (bytes)
    char* ws = (char*)d_ws;
    int*            gcursor   = (int*)(ws + 0);              // 2,048
    int*            ewords    = (int*)(ws + 2048);           // 391*2816*4 = 4,404,224
    float*          h1        = (float*)(ws + 4406272);      // 3,200,000 (live during sortgemm1!)
    unsigned short* eidx      = (unsigned short*)(ws + 7606272);   // 2,202,112
    int*            row_start = (int*)(ws + 9808384);        // 200,000
    int*            deg       = (int*)(ws + 10008384);       // 200,000
    float*          dinv      = (float*)(ws + 10208384);     // 200,000
    float*          z1s       = (float*)(ws + 10408384);     // 3,200,000
    // total ~13.6 MB

    const int NCHUNK = (E + CHUNK - 1) / CHUNK;   // 391

    hipMemsetAsync(gcursor, 0, NBUCKET * sizeof(int), stream);
    k_part<<<NCHUNK, 512, 0, stream>>>(src, dst, gcursor, ewords, E);
    k_sortgemm1<<<NBUCKET + N_NODES / 16, 256, 0, stream>>>(ewords, gcursor, eidx,
                                                            row_start, deg, dinv, x, W1, h1);
    k_agg1<<<N_NODES / 4, 256, 0, stream>>>(h1, row_start, deg, eidx, dinv, b1, z1s);
    k_aggmm<<<(N_NODES + 63) / 64, 256, 0, stream>>>(z1s, row_start, deg, eidx, dinv,
                                                     W2, b2, out);
}

// Round 6
// 153.579 us; speedup vs baseline: 1.1038x; 1.1038x over previous
//
#include <hip/hip_runtime.h>

#define N_NODES 50000
#define NPB 128                               // nodes per bucket
#define NBUCKET ((N_NODES + NPB - 1) / NPB)   // 391
#define CAP 2816                              // edges per bucket region (mean 2048 + ~17 sigma)
#define CHUNK 4096                            // edges per partition block
#define EPT 8                                 // edges per thread in part role (CHUNK/512)
#define G1_NPB 32                             // gemm1 nodes per block (512 threads)
#define NG1 ((N_NODES + G1_NPB - 1) / G1_NPB) // 1563
#define NCHUNK ((800000 + CHUNK - 1) / CHUNK) // 196

// ================= fused: edge partition (blocks < NCHUNK) | gemm1 (rest) =========
// edge word: src(16b) | ldst(7b)<<16 | bucket(9b)<<23   (src < 50000 < 65536)
// gcursor pre-zeroed by memset; holds RELATIVE per-bucket fill counts.
// gemm1 writes RAW h1 = x @ W1 (prescale happens in k_sortscale).

__global__ __launch_bounds__(512) void k_partgemm1(const int* __restrict__ src,
                                                   const int* __restrict__ dst,
                                                   int* __restrict__ gcursor,
                                                   int* __restrict__ ewords, int E,
                                                   const float* __restrict__ x,
                                                   const float* __restrict__ W1,
                                                   float* __restrict__ h1) {
    __shared__ __align__(16) char smem[25344 + 64];
    int tid = threadIdx.x;

    if (blockIdx.x < NCHUNK) {
        // ---- partition role ----
        int* words  = (int*)smem;                      // CHUNK*4 = 16384
        int* hist   = (int*)(smem + 16384);            // 2048
        int* lstart = (int*)(smem + 16384 + 2048);     // 2048
        int* gbase  = (int*)(smem + 16384 + 4096);     // 2048
        int* wsum   = (int*)(smem + 16384 + 6144);     // 32

        int cbase = blockIdx.x * CHUNK;
        int count = min(CHUNK, E - cbase);

        hist[tid] = 0;
        __syncthreads();

        // phase 1: load edges, histogram buckets
        int w[EPT];
        if (cbase + CHUNK <= E) {
#pragma unroll
            for (int hh = 0; hh < 2; hh++) {
                int4 s4 = ((const int4*)(src + cbase))[tid + 512 * hh];
                int4 d4 = ((const int4*)(dst + cbase))[tid + 512 * hh];
                int ss[4] = {s4.x, s4.y, s4.z, s4.w};
                int dd[4] = {d4.x, d4.y, d4.z, d4.w};
#pragma unroll
                for (int c = 0; c < 4; c++) {
                    int b = dd[c] >> 7;
                    w[hh * 4 + c] = ss[c] | ((dd[c] & 127) << 16) | (b << 23);
                    atomicAdd(&hist[b], 1);
                }
            }
        } else {
#pragma unroll
            for (int r = 0; r < EPT; r++) {
                int i = tid * EPT + r;
                if (i < count) {
                    int s = src[cbase + i];
                    int d = dst[cbase + i];
                    int b = d >> 7;
                    w[r] = s | ((d & 127) << 16) | (b << 23);
                    atomicAdd(&hist[b], 1);
                } else {
                    w[r] = -1;
                }
            }
        }
        __syncthreads();

        // phase 2: exclusive scan of hist[512] (wave shfl scan + cross-wave fixup)
        int h = hist[tid];
        int lane = tid & 63;
        int v = h;
#pragma unroll
        for (int off = 1; off < 64; off <<= 1) {
            int t = __shfl_up(v, off, 64);   // unconditional shfl, predicated add: exec-safe
            if (lane >= off) v += t;
        }
        if (lane == 63) wsum[tid >> 6] = v;
        __syncthreads();
        int woff = 0;
        int wv = tid >> 6;
        for (int i = 0; i < wv; i++) woff += wsum[i];
        int excl = v + woff - h;
        hist[tid] = excl;       // becomes local cursor
        lstart[tid] = excl;
        __syncthreads();

        // phase 3: scatter words into LDS grouped by bucket
#pragma unroll
        for (int r = 0; r < EPT; r++) {
            if (w[r] != -1) {
                int b = ((unsigned)w[r]) >> 23;
                int pos = atomicAdd(&hist[b], 1);
                words[pos] = w[r];
            }
        }
        __syncthreads();

        // phase 4: one global cursor bump per bucket per chunk
        if (tid < NBUCKET) {
            int nb = hist[tid] - lstart[tid];
            gbase[tid] = (nb > 0) ? atomicAdd(&gcursor[tid], nb) : 0;
        }
        __syncthreads();

        // phase 5: coalesced run write-out (runs avg ~10.5 edges)
        for (int i = tid; i < count; i += 512) {
            int ww = words[i];
            int b = ((unsigned)ww) >> 23;
            ewords[b * CAP + gbase[b] + (i - lstart[b])] = ww;
        }
    } else {
        // ---- gemm1 role: 32 nodes per block ----
        float* sx  = (float*)smem;              // 32*132 floats = 16896 B
        float* swT = sx + 32 * 132;             // 16*132 floats = 8448 B
        int n0 = (blockIdx.x - NCHUNK) * G1_NPB;

        // W1 [128,16] -> swT[j*132+k]
        {
            float4 v = ((const float4*)W1)[tid];
            int k = tid >> 2;
            int j4 = (tid & 3) << 2;
            swT[(j4 + 0) * 132 + k] = v.x;
            swT[(j4 + 1) * 132 + k] = v.y;
            swT[(j4 + 2) * 132 + k] = v.z;
            swT[(j4 + 3) * 132 + k] = v.w;
        }
        // x tile: 32 rows x 128 cols = 1024 float4
        const float4* x4 = (const float4*)(x + (size_t)n0 * 128);
#pragma unroll
        for (int r = 0; r < 2; r++) {
            int q = tid + 512 * r;
            int row = q >> 5;
            if (n0 + row < N_NODES) {
                float4 v = x4[q];
                int k = (q & 31) << 2;
                *(float4*)&sx[row * 132 + k] = v;
            }
        }
        __syncthreads();

        int node = tid >> 4;
        int j = tid & 15;
        float acc = 0.f;
#pragma unroll
        for (int k = 0; k < 128; k += 4) {
            float4 a = *(const float4*)&sx[node * 132 + k];
            float4 bb = *(const float4*)&swT[j * 132 + k];
            acc = fmaf(a.x, bb.x, acc);
            acc = fmaf(a.y, bb.y, acc);
            acc = fmaf(a.z, bb.z, acc);
            acc = fmaf(a.w, bb.w, acc);
        }
        int n = n0 + node;
        if (n < N_NODES) h1[(size_t)n * 16 + j] = acc;
    }
}

// ================= per-bucket sort + deg/dinv/row_start + prescale h1 =============

__global__ __launch_bounds__(256) void k_sortscale(const int* __restrict__ ewords,
                                                   const int* __restrict__ gcursor,
                                                   unsigned short* __restrict__ eidx,
                                                   int* __restrict__ row_start,
                                                   int* __restrict__ deg,
                                                   float* __restrict__ dinv,
                                                   float* __restrict__ h1) {
    __shared__ unsigned short sorted[CAP];   // 5632 B
    __shared__ int hist[NPB];
    __shared__ int sc[NPB];
    __shared__ float sdinv[NPB];
    int tid = threadIdx.x;
    int b = blockIdx.x;
    int base = b * CAP;
    int count = gcursor[b];                  // relative count

    if (tid < NPB) hist[tid] = 0;
    __syncthreads();

    int w[(CAP + 255) / 256];   // 11
#pragma unroll
    for (int r = 0; r < (CAP + 255) / 256; r++) {
        int i = tid + 256 * r;
        if (i < count) {
            int ww = ewords[base + i];
            w[r] = ww;
            atomicAdd(&hist[(ww >> 16) & 127], 1);
        } else {
            w[r] = -1;
        }
    }
    __syncthreads();

    // exclusive scan of hist[128]
    int v = 0;
    if (tid < NPB) { v = hist[tid]; sc[tid] = v; }
    __syncthreads();
    for (int off = 1; off < NPB; off <<= 1) {
        int t = 0;
        if (tid < NPB && tid >= off) t = sc[tid - off];
        __syncthreads();
        if (tid < NPB) sc[tid] += t;
        __syncthreads();
    }
    if (tid < NPB) {
        int excl = sc[tid] - v;
        int node = b * NPB + tid;
        float dv = rsqrtf((float)(v + 1));
        sdinv[tid] = dv;
        if (node < N_NODES) {
            row_start[node] = base + excl;
            deg[node] = v;
            dinv[node] = dv;
        }
        hist[tid] = excl;   // cursor
    }
    __syncthreads();

    // scatter into LDS sorted by local dst
#pragma unroll
    for (int r = 0; r < (CAP + 255) / 256; r++) {
        if (w[r] != -1) {
            int ldst = (w[r] >> 16) & 127;
            int pos = atomicAdd(&hist[ldst], 1);
            sorted[pos] = (unsigned short)(w[r] & 0xFFFF);
        }
    }
    __syncthreads();

    // coalesced eidx write-out
    for (int i = tid; i < count; i += 256) eidx[base + i] = sorted[i];

    // prescale this bucket's h1 rows: h1[node] *= dinv[node]  (128 rows x 16 f = 512 float4)
    float4* h4 = (float4*)(h1 + (size_t)b * NPB * 16);
    int nvalid4 = (b == NBUCKET - 1) ? (N_NODES - b * NPB) * 4 : NPB * 4;
#pragma unroll
    for (int r = 0; r < 2; r++) {
        int q = tid + 256 * r;
        if (q < nvalid4) {
            float dv = sdinv[q >> 2];
            float4 vv = h4[q];
            vv.x *= dv; vv.y *= dv; vv.z *= dv; vv.w *= dv;
            h4[q] = vv;
        }
    }
}

// ================= agg1: one wave per node, EXEC-SAFE shfl-edge gather, relu ======
// z1s[n] = dinv[n] * relu(dinv[n]*(sum_e h1s[src] + h1s[n]) + b1)   (h1s prescaled)
// shfl discipline: every __shfl executed by ALL 64 lanes (uniform trip count,
// clamped source index); only the accumulate is predicated.

__global__ __launch_bounds__(256) void k_agg1(const float* __restrict__ h1s,
                                              const int* __restrict__ row_start,
                                              const int* __restrict__ deg,
                                              const unsigned short* __restrict__ eidx,
                                              const float* __restrict__ dinv,
                                              const float* __restrict__ b1,
                                              float* __restrict__ z1s) {
    int lane = threadIdx.x & 63;
    int node = blockIdx.x * 4 + (threadIdx.x >> 6);   // grid = N/4 exactly
    int f = lane & 15;
    int sub = lane >> 4;

    int start = row_start[node];
    int d = deg[node];
    int m = min(d, 64);                                 // wave-uniform

    int e = 0;
    if (m > 0) e = (int)eidx[start + min(lane, m - 1)]; // wave-uniform branch, full exec

    float a0 = 0.f, a1 = 0.f;
    int iters = (m + 7) >> 3;                           // wave-uniform trip count
    int i = sub;
    for (int t = 0; t < iters; t++, i += 8) {
        int s0 = __shfl(e, min(i, m - 1), 64);          // full-exec shfl
        int s1 = __shfl(e, min(i + 4, m - 1), 64);
        float v0 = h1s[s0 * 16 + f];
        float v1 = h1s[s1 * 16 + f];
        if (i < m) a0 += v0;
        if (i + 4 < m) a1 += v1;
    }
    for (int q = 64 + sub; q < d; q += 4)               // safety tail (deg>64: ~never)
        a0 += h1s[(int)eidx[start + q] * 16 + f];
    float acc = a0 + a1;

    acc += __shfl_xor(acc, 16, 64);
    acc += __shfl_xor(acc, 32, 64);
    acc += h1s[node * 16 + f];                          // self loop (prescaled)

    float dv = dinv[node];
    float z = fmaxf(fmaf(dv, acc, b1[f]), 0.f);
    if (sub == 0) z1s[node * 16 + f] = dv * z;          // prescaled for layer 2
}

// ================= fused agg2 + gemm2: 4 nodes per wave ===========================
// s2 = dinv[n]*(sum_e z1s[src] + z1s[n]);  out[n][j] = b2[j] + sum_k s2[k]*W2[k][j]

__global__ __launch_bounds__(256) void k_aggmm(const float* __restrict__ z1s,
                                               const int* __restrict__ row_start,
                                               const int* __restrict__ deg,
                                               const unsigned short* __restrict__ eidx,
                                               const float* __restrict__ dinv,
                                               const float* __restrict__ W2,
                                               const float* __restrict__ b2,
                                               float* __restrict__ out) {
    __shared__ float sw2[16 * 128];   // [k][j], 8 KB
    __shared__ float sb2[128];
    int tid = threadIdx.x;

    ((float4*)sw2)[tid] = ((const float4*)W2)[tid];
    ((float4*)sw2)[tid + 256] = ((const float4*)W2)[tid + 256];
    if (tid < 32) ((float4*)sb2)[tid] = ((const float4*)b2)[tid];
    __syncthreads();

    int lane = tid & 63;
    int gw = blockIdx.x * 4 + (tid >> 6);   // 0..12499
    int f = lane & 15;
    int sub = lane >> 4;

#pragma unroll 1
    for (int t = 0; t < 4; t++) {
        int node = gw + t * 12500;          // 4 independent nodes per wave

        int start = row_start[node];
        int d = deg[node];
        int m = min(d, 64);                 // wave-uniform

        int e = 0;
        if (m > 0) e = (int)eidx[start + min(lane, m - 1)];

        float a0 = 0.f, a1 = 0.f;
        int iters = (m + 7) >> 3;
        int i = sub;
        for (int u = 0; u < iters; u++, i += 8) {
            int s0 = __shfl(e, min(i, m - 1), 64);
            int s1 = __shfl(e, min(i + 4, m - 1), 64);
            float v0 = z1s[s0 * 16 + f];
            float v1 = z1s[s1 * 16 + f];
            if (i < m) a0 += v0;
            if (i + 4 < m) a1 += v1;
        }
        for (int q = 64 + sub; q < d; q += 4)
            a0 += z1s[(int)eidx[start + q] * 16 + f];
        float acc = a0 + a1;

        acc += __shfl_xor(acc, 16, 64);
        acc += __shfl_xor(acc, 32, 64);
        acc += z1s[node * 16 + f];          // self loop (prescaled)
        float s2 = dinv[node] * acc;        // lane k (k<16) holds s2[k]

        float o0 = sb2[lane];
        float o1 = sb2[lane + 64];
#pragma unroll
        for (int k = 0; k < 16; k++) {
            float sk = __shfl(s2, k, 64);   // full exec here (converged)
            o0 = fmaf(sk, sw2[k * 128 + lane], o0);
            o1 = fmaf(sk, sw2[k * 128 + 64 + lane], o1);
        }
        out[(size_t)node * 128 + lane] = o0;
        out[(size_t)node * 128 + 64 + lane] = o1;
    }
}

// ================= launch =========================================================

extern "C" void kernel_launch(void* const* d_in, const int* in_sizes, int n_in,
                              void* d_out, int out_size, void* d_ws, size_t ws_size,
                              hipStream_t stream) {
    const float* x  = (const float*)d_in[0];
    const int*   ei = (const int*)d_in[1];
    const float* W1 = (const float*)d_in[2];
    const float* b1 = (const float*)d_in[3];
    const float* W2 = (const float*)d_in[4];
    const float* b2 = (const float*)d_in[5];
    float* out = (float*)d_out;

    const int E = in_sizes[1] / 2;            // 800000
    const int* src = ei;
    const int* dst = ei + E;

    // workspace layout (bytes)
    char* ws = (char*)d_ws;
    int*            gcursor   = (int*)(ws + 0);              // 2,048
    int*            ewords    = (int*)(ws + 2048);           // 391*2816*4 = 4,404,224
    float*          h1        = (float*)(ws + 4406272);      // 3,200,000
    unsigned short* eidx      = (unsigned short*)(ws + 7606272);   // 2,202,112
    int*            row_start = (int*)(ws + 9808384);        // 200,000
    int*            deg       = (int*)(ws + 10008384);       // 200,000
    float*          dinv      = (float*)(ws + 10208384);     // 200,000
    float*          z1s       = (float*)(ws + 10408384);     // 3,200,000
    // total ~13.6 MB

    hipMemsetAsync(gcursor, 0, NBUCKET * sizeof(int), stream);
    k_partgemm1<<<NCHUNK + NG1, 512, 0, stream>>>(src, dst, gcursor, ewords, E, x, W1, h1);
    k_sortscale<<<NBUCKET, 256, 0, stream>>>(ewords, gcursor, eidx, row_start, deg, dinv, h1);
    k_agg1<<<N_NODES / 4, 256, 0, stream>>>(h1, row_start, deg, eidx, dinv, b1, z1s);
    k_aggmm<<<(N_NODES / 4) / 4, 256, 0, stream>>>(z1s, row_start, deg, eidx, dinv, W2, b2, out);
}

// Round 7
// 149.455 us; speedup vs baseline: 1.1343x; 1.0276x over previous
//
#include <hip/hip_runtime.h>

#define N_NODES 50000
#define NPB 128                               // nodes per bucket
#define NBUCKET ((N_NODES + NPB - 1) / NPB)   // 391
#define CAP 2816                              // edges per bucket region (mean 2048 + ~17 sigma)
#define CHUNK 4096                            // edges per partition block
#define EPT 8                                 // edges per thread in part role (CHUNK/512)
#define G1_NPB 32                             // gemm1 nodes per block (512 threads)
#define NG1 ((N_NODES + G1_NPB - 1) / G1_NPB) // 1563
#define NCHUNK ((800000 + CHUNK - 1) / CHUNK) // 196

// ================= fused: edge partition (blocks < NCHUNK) | gemm1 (rest) =========
// edge word: src(16b) | ldst(7b)<<16 | bucket(9b)<<23   (src < 50000 < 65536)
// gcursor pre-zeroed by memset; holds RELATIVE per-bucket fill counts.
// gemm1 writes RAW h1 = x @ W1 (prescale happens in k_sortscale).

__global__ __launch_bounds__(512) void k_partgemm1(const int* __restrict__ src,
                                                   const int* __restrict__ dst,
                                                   int* __restrict__ gcursor,
                                                   int* __restrict__ ewords, int E,
                                                   const float* __restrict__ x,
                                                   const float* __restrict__ W1,
                                                   float* __restrict__ h1) {
    __shared__ __align__(16) char smem[25344 + 64];
    int tid = threadIdx.x;

    if (blockIdx.x < NCHUNK) {
        // ---- partition role ----
        int* words  = (int*)smem;                      // CHUNK*4 = 16384
        int* hist   = (int*)(smem + 16384);            // 2048
        int* lstart = (int*)(smem + 16384 + 2048);     // 2048
        int* gbase  = (int*)(smem + 16384 + 4096);     // 2048
        int* wsum   = (int*)(smem + 16384 + 6144);     // 32

        int cbase = blockIdx.x * CHUNK;
        int count = min(CHUNK, E - cbase);

        hist[tid] = 0;
        __syncthreads();

        // phase 1: load edges, histogram buckets
        int w[EPT];
        if (cbase + CHUNK <= E) {
#pragma unroll
            for (int hh = 0; hh < 2; hh++) {
                int4 s4 = ((const int4*)(src + cbase))[tid + 512 * hh];
                int4 d4 = ((const int4*)(dst + cbase))[tid + 512 * hh];
                int ss[4] = {s4.x, s4.y, s4.z, s4.w};
                int dd[4] = {d4.x, d4.y, d4.z, d4.w};
#pragma unroll
                for (int c = 0; c < 4; c++) {
                    int b = dd[c] >> 7;
                    w[hh * 4 + c] = ss[c] | ((dd[c] & 127) << 16) | (b << 23);
                    atomicAdd(&hist[b], 1);
                }
            }
        } else {
#pragma unroll
            for (int r = 0; r < EPT; r++) {
                int i = tid * EPT + r;
                if (i < count) {
                    int s = src[cbase + i];
                    int d = dst[cbase + i];
                    int b = d >> 7;
                    w[r] = s | ((d & 127) << 16) | (b << 23);
                    atomicAdd(&hist[b], 1);
                } else {
                    w[r] = -1;
                }
            }
        }
        __syncthreads();

        // phase 2: exclusive scan of hist[512] (wave shfl scan + cross-wave fixup)
        int h = hist[tid];
        int lane = tid & 63;
        int v = h;
#pragma unroll
        for (int off = 1; off < 64; off <<= 1) {
            int t = __shfl_up(v, off, 64);   // unconditional shfl, predicated add: exec-safe
            if (lane >= off) v += t;
        }
        if (lane == 63) wsum[tid >> 6] = v;
        __syncthreads();
        int woff = 0;
        int wv = tid >> 6;
        for (int i = 0; i < wv; i++) woff += wsum[i];
        int excl = v + woff - h;
        hist[tid] = excl;       // becomes local cursor
        lstart[tid] = excl;
        __syncthreads();

        // phase 3: scatter words into LDS grouped by bucket
#pragma unroll
        for (int r = 0; r < EPT; r++) {
            if (w[r] != -1) {
                int b = ((unsigned)w[r]) >> 23;
                int pos = atomicAdd(&hist[b], 1);
                words[pos] = w[r];
            }
        }
        __syncthreads();

        // phase 4: one global cursor bump per bucket per chunk
        if (tid < NBUCKET) {
            int nb = hist[tid] - lstart[tid];
            gbase[tid] = (nb > 0) ? atomicAdd(&gcursor[tid], nb) : 0;
        }
        __syncthreads();

        // phase 5: coalesced run write-out (runs avg ~10.5 edges)
        for (int i = tid; i < count; i += 512) {
            int ww = words[i];
            int b = ((unsigned)ww) >> 23;
            ewords[b * CAP + gbase[b] + (i - lstart[b])] = ww;
        }
    } else {
        // ---- gemm1 role: 32 nodes per block ----
        float* sx  = (float*)smem;              // 32*132 floats = 16896 B
        float* swT = sx + 32 * 132;             // 16*132 floats = 8448 B
        int n0 = (blockIdx.x - NCHUNK) * G1_NPB;

        // W1 [128,16] -> swT[j*132+k]
        {
            float4 v = ((const float4*)W1)[tid];
            int k = tid >> 2;
            int j4 = (tid & 3) << 2;
            swT[(j4 + 0) * 132 + k] = v.x;
            swT[(j4 + 1) * 132 + k] = v.y;
            swT[(j4 + 2) * 132 + k] = v.z;
            swT[(j4 + 3) * 132 + k] = v.w;
        }
        // x tile: 32 rows x 128 cols = 1024 float4
        const float4* x4 = (const float4*)(x + (size_t)n0 * 128);
#pragma unroll
        for (int r = 0; r < 2; r++) {
            int q = tid + 512 * r;
            int row = q >> 5;
            if (n0 + row < N_NODES) {
                float4 v = x4[q];
                int k = (q & 31) << 2;
                *(float4*)&sx[row * 132 + k] = v;
            }
        }
        __syncthreads();

        int node = tid >> 4;
        int j = tid & 15;
        float acc = 0.f;
#pragma unroll
        for (int k = 0; k < 128; k += 4) {
            float4 a = *(const float4*)&sx[node * 132 + k];
            float4 bb = *(const float4*)&swT[j * 132 + k];
            acc = fmaf(a.x, bb.x, acc);
            acc = fmaf(a.y, bb.y, acc);
            acc = fmaf(a.z, bb.z, acc);
            acc = fmaf(a.w, bb.w, acc);
        }
        int n = n0 + node;
        if (n < N_NODES) h1[(size_t)n * 16 + j] = acc;
    }
}

// ================= per-bucket sort + deg/dinv/row_start + prescale h1 =============
// 512 threads/block (round 7: was 256) — halves the latency-bound load/scatter path.

__global__ __launch_bounds__(512) void k_sortscale(const int* __restrict__ ewords,
                                                   const int* __restrict__ gcursor,
                                                   unsigned short* __restrict__ eidx,
                                                   int* __restrict__ row_start,
                                                   int* __restrict__ deg,
                                                   float* __restrict__ dinv,
                                                   float* __restrict__ h1) {
    __shared__ unsigned short sorted[CAP];   // 5632 B
    __shared__ int hist[NPB];
    __shared__ int sc[NPB];
    __shared__ float sdinv[NPB];
    int tid = threadIdx.x;
    int b = blockIdx.x;
    int base = b * CAP;
    int count = gcursor[b];                  // relative count

    if (tid < NPB) hist[tid] = 0;
    __syncthreads();

    int w[(CAP + 511) / 512];   // 6
#pragma unroll
    for (int r = 0; r < (CAP + 511) / 512; r++) {
        int i = tid + 512 * r;
        if (i < count) {
            int ww = ewords[base + i];
            w[r] = ww;
            atomicAdd(&hist[(ww >> 16) & 127], 1);
        } else {
            w[r] = -1;
        }
    }
    __syncthreads();

    // exclusive scan of hist[128] (uniform barriers, guarded work)
    int v = 0;
    if (tid < NPB) { v = hist[tid]; sc[tid] = v; }
    __syncthreads();
    for (int off = 1; off < NPB; off <<= 1) {
        int t = 0;
        if (tid < NPB && tid >= off) t = sc[tid - off];
        __syncthreads();
        if (tid < NPB) sc[tid] += t;
        __syncthreads();
    }
    if (tid < NPB) {
        int excl = sc[tid] - v;
        int node = b * NPB + tid;
        float dv = rsqrtf((float)(v + 1));
        sdinv[tid] = dv;
        if (node < N_NODES) {
            row_start[node] = base + excl;
            deg[node] = v;
            dinv[node] = dv;
        }
        hist[tid] = excl;   // cursor
    }
    __syncthreads();

    // scatter into LDS sorted by local dst
#pragma unroll
    for (int r = 0; r < (CAP + 511) / 512; r++) {
        if (w[r] != -1) {
            int ldst = (w[r] >> 16) & 127;
            int pos = atomicAdd(&hist[ldst], 1);
            sorted[pos] = (unsigned short)(w[r] & 0xFFFF);
        }
    }
    __syncthreads();

    // coalesced eidx write-out
    for (int i = tid; i < count; i += 512) eidx[base + i] = sorted[i];

    // prescale this bucket's h1 rows: h1[node] *= dinv[node]  (128 rows x 16 f = 512 float4)
    float4* h4 = (float4*)(h1 + (size_t)b * NPB * 16);
    int nvalid4 = (b == NBUCKET - 1) ? (N_NODES - b * NPB) * 4 : NPB * 4;
    if (tid < nvalid4) {
        float dv = sdinv[tid >> 2];
        float4 vv = h4[tid];
        vv.x *= dv; vv.y *= dv; vv.z *= dv; vv.w *= dv;
        h4[tid] = vv;
    }
}

// ================= agg1: one wave per node, EXEC-SAFE shfl-edge gather, relu ======
// z1s[n] = dinv[n] * relu(dinv[n]*(sum_e h1s[src] + h1s[n]) + b1)   (h1s prescaled)

__global__ __launch_bounds__(256) void k_agg1(const float* __restrict__ h1s,
                                              const int* __restrict__ row_start,
                                              const int* __restrict__ deg,
                                              const unsigned short* __restrict__ eidx,
                                              const float* __restrict__ dinv,
                                              const float* __restrict__ b1,
                                              float* __restrict__ z1s) {
    int lane = threadIdx.x & 63;
    int node = blockIdx.x * 4 + (threadIdx.x >> 6);   // grid = N/4 exactly
    int f = lane & 15;
    int sub = lane >> 4;

    int start = row_start[node];
    int d = deg[node];
    int m = min(d, 64);                                 // wave-uniform

    int e = 0;
    if (m > 0) e = (int)eidx[start + min(lane, m - 1)]; // wave-uniform branch, full exec

    float a0 = 0.f, a1 = 0.f;
    int iters = (m + 7) >> 3;                           // wave-uniform trip count
    int i = sub;
    for (int t = 0; t < iters; t++, i += 8) {
        int s0 = __shfl(e, min(i, m - 1), 64);          // full-exec shfl
        int s1 = __shfl(e, min(i + 4, m - 1), 64);
        float v0 = h1s[s0 * 16 + f];
        float v1 = h1s[s1 * 16 + f];
        if (i < m) a0 += v0;
        if (i + 4 < m) a1 += v1;
    }
    for (int q = 64 + sub; q < d; q += 4)               // safety tail (deg>64: ~never)
        a0 += h1s[(int)eidx[start + q] * 16 + f];
    float acc = a0 + a1;

    acc += __shfl_xor(acc, 16, 64);
    acc += __shfl_xor(acc, 32, 64);
    acc += h1s[node * 16 + f];                          // self loop (prescaled)

    float dv = dinv[node];
    float z = fmaxf(fmaf(dv, acc, b1[f]), 0.f);
    if (sub == 0) z1s[node * 16 + f] = dv * z;          // prescaled for layer 2
}

// ================= fused agg2 + gemm2: ONE node per wave (round 7) ================
// 512-thread blocks: 8 waves, 8 nodes/block; W2 LDS tile amortized over 8 waves.
// s2 = dinv[n]*(sum_e z1s[src] + z1s[n]);  out[n][j] = b2[j] + sum_k s2[k]*W2[k][j]

__global__ __launch_bounds__(512) void k_aggmm(const float* __restrict__ z1s,
                                               const int* __restrict__ row_start,
                                               const int* __restrict__ deg,
                                               const unsigned short* __restrict__ eidx,
                                               const float* __restrict__ dinv,
                                               const float* __restrict__ W2,
                                               const float* __restrict__ b2,
                                               float* __restrict__ out) {
    __shared__ float sw2[16 * 128];   // [k][j], 8 KB
    __shared__ float sb2[128];
    int tid = threadIdx.x;

    ((float4*)sw2)[tid] = ((const float4*)W2)[tid];   // 512 float4 = full 16x128
    if (tid < 32) ((float4*)sb2)[tid] = ((const float4*)b2)[tid];
    __syncthreads();

    int lane = tid & 63;
    int node = blockIdx.x * 8 + (tid >> 6);   // grid = N/8 exactly (6250)
    int f = lane & 15;
    int sub = lane >> 4;

    int start = row_start[node];
    int d = deg[node];
    int m = min(d, 64);                       // wave-uniform

    int e = 0;
    if (m > 0) e = (int)eidx[start + min(lane, m - 1)];

    float a0 = 0.f, a1 = 0.f;
    int iters = (m + 7) >> 3;
    int i = sub;
    for (int u = 0; u < iters; u++, i += 8) {
        int s0 = __shfl(e, min(i, m - 1), 64);
        int s1 = __shfl(e, min(i + 4, m - 1), 64);
        float v0 = z1s[s0 * 16 + f];
        float v1 = z1s[s1 * 16 + f];
        if (i < m) a0 += v0;
        if (i + 4 < m) a1 += v1;
    }
    for (int q = 64 + sub; q < d; q += 4)
        a0 += z1s[(int)eidx[start + q] * 16 + f];
    float acc = a0 + a1;

    acc += __shfl_xor(acc, 16, 64);
    acc += __shfl_xor(acc, 32, 64);
    acc += z1s[node * 16 + f];                // self loop (prescaled)
    float s2 = dinv[node] * acc;              // lane k (k<16) holds s2[k]

    float o0 = sb2[lane];
    float o1 = sb2[lane + 64];
#pragma unroll
    for (int k = 0; k < 16; k++) {
        float sk = __shfl(s2, k, 64);         // full exec (converged)
        o0 = fmaf(sk, sw2[k * 128 + lane], o0);
        o1 = fmaf(sk, sw2[k * 128 + 64 + lane], o1);
    }
    out[(size_t)node * 128 + lane] = o0;
    out[(size_t)node * 128 + 64 + lane] = o1;
}

// ================= launch =========================================================

extern "C" void kernel_launch(void* const* d_in, const int* in_sizes, int n_in,
                              void* d_out, int out_size, void* d_ws, size_t ws_size,
                              hipStream_t stream) {
    const float* x  = (const float*)d_in[0];
    const int*   ei = (const int*)d_in[1];
    const float* W1 = (const float*)d_in[2];
    const float* b1 = (const float*)d_in[3];
    const float* W2 = (const float*)d_in[4];
    const float* b2 = (const float*)d_in[5];
    float* out = (float*)d_out;

    const int E = in_sizes[1] / 2;            // 800000
    const int* src = ei;
    const int* dst = ei + E;

    // workspace layout (bytes)
    char* ws = (char*)d_ws;
    int*            gcursor   = (int*)(ws + 0);              // 2,048
    int*            ewords    = (int*)(ws + 2048);           // 391*2816*4 = 4,404,224
    float*          h1        = (float*)(ws + 4406272);      // 3,200,000
    unsigned short* eidx      = (unsigned short*)(ws + 7606272);   // 2,202,112
    int*            row_start = (int*)(ws + 9808384);        // 200,000
    int*            deg       = (int*)(ws + 10008384);       // 200,000
    float*          dinv      = (float*)(ws + 10208384);     // 200,000
    float*          z1s       = (float*)(ws + 10408384);     // 3,200,000
    // total ~13.6 MB

    hipMemsetAsync(gcursor, 0, NBUCKET * sizeof(int), stream);
    k_partgemm1<<<NCHUNK + NG1, 512, 0, stream>>>(src, dst, gcursor, ewords, E, x, W1, h1);
    k_sortscale<<<NBUCKET, 512, 0, stream>>>(ewords, gcursor, eidx, row_start, deg, dinv, h1);
    k_agg1<<<N_NODES / 4, 256, 0, stream>>>(h1, row_start, deg, eidx, dinv, b1, z1s);
    k_aggmm<<<N_NODES / 8, 512, 0, stream>>>(z1s, row_start, deg, eidx, dinv, W2, b2, out);
}